// Round 7
// baseline (426.173 us; speedup 1.0000x reference)
//
#include <hip/hip_runtime.h>

#define BB 64
#define C1 3
#define LIN 8192
#define O1 6
#define KK1 80
#define LP1 4058
#define O2 16
#define LP2 2028
#define NFLAT 32448    // 16*2028
#define H1 120
#define H2 84
#define NOUT 10

#define NBLK 256
#define THR 1024
#define TP1 1016       // p1 values produced per block (covers 507 conv2 outputs)
#define DW 1056        // staged x pairs per channel
#define QJ 507         // conv2 outputs per block (4*507 = 2028)

typedef _Float16 h2v __attribute__((ext_vector_type(2)));
typedef _Float16 f16x8 __attribute__((ext_vector_type(8)));
typedef float f32x4 __attribute__((ext_vector_type(4)));
#define BIGH ((_Float16)30000.0f)

__device__ __forceinline__ h2v bch2(float f) { return __builtin_bit_cast(h2v, f); }

// ---------------- prep: zero h1 + barriers, pack w1 -> h2 pairs ----------------
__global__ __launch_bounds__(1024) void k_prep(const float* __restrict__ w1,
                                               float* __restrict__ whb,
                                               float* __restrict__ h1,
                                               int* __restrict__ bar) {
  const int base = blockIdx.x * 1024 + threadIdx.x;
  for (int idx = base; idx < H1 * BB; idx += 8192) h1[idx] = 0.f;
  if (base < 16) bar[base] = 0;
  if (base < (O1 * C1) * (KK1 / 2)) {
    const int oc = base / 40;
    const int m  = base - oc * 40;
    h2v v;
    v.x = (_Float16)w1[oc * KK1 + 2 * m];
    v.y = (_Float16)w1[oc * KK1 + 2 * m + 1];
    whb[base] = __builtin_bit_cast(float, v);
  }
}

// ---------------- grid barrier: per-stage counter, no reset ----------------
__device__ __forceinline__ void gbar(int* bar, int k) {
  __threadfence();                 // push this thread's global stores (L2 wb, device scope)
  __syncthreads();
  if (threadIdx.x == 0) {
    __hip_atomic_fetch_add(&bar[k], 1, __ATOMIC_RELEASE, __HIP_MEMORY_SCOPE_AGENT);
    while (__hip_atomic_load(&bar[k], __ATOMIC_ACQUIRE, __HIP_MEMORY_SCOPE_AGENT) < NBLK)
      __builtin_amdgcn_s_sleep(2);
  }
  __syncthreads();
  __threadfence();                 // invalidate caches before reading others' data
}

// ---------------- mega: conv1+pool+conv2+pool | fc1(MFMA,atomic) | head ----------------
__global__ __launch_bounds__(THR, 4) void k_mega(
    const float* __restrict__ x,
    const float* __restrict__ whb,
    const float* __restrict__ w2,
    const float* __restrict__ fc1w,
    const float* __restrict__ fc1b,
    const float* __restrict__ fc2w,
    const float* __restrict__ fc2b,
    const float* __restrict__ fc3w,
    const float* __restrict__ fc3b,
    _Float16* __restrict__ p2h,
    float* __restrict__ h1,
    int* __restrict__ bar,
    float* __restrict__ out) {
  __shared__ float smem[12720];    // 50.9 KB: A(3168) | B(3168) | P1(6096) | W2(288)
  const int blk = blockIdx.x;
  const int tid = threadIdx.x;

  // ================= S1+S2: per (b, quarter) conv chain, p1 stays in LDS =================
  {
    const int b  = blk >> 2;
    const int qq = blk & 3;
    const int t0 = qq * 1014;              // first p1 index this block must produce
    float* As = smem;                      // [C1][DW] h2(x[2t],x[2t+1])
    float* Bs = smem + C1 * DW;            // [C1][DW] h2(x[2t+1],x[2t+2])
    float* P1 = smem + 2 * C1 * DW;        // [O1][TP1] fp32
    float* W2 = P1 + O1 * TP1;             // [288]

    for (int idx = tid; idx < O2 * O1 * 3; idx += THR) W2[idx] = w2[idx];
    for (int idx = tid; idx < C1 * DW; idx += THR) {
      const int c = idx / DW;
      const int d = idx - c * DW;
      const int E = 2 * t0 + 2 * d - 2;    // padding = 2
      const float* xc = x + ((size_t)b * C1 + c) * LIN;
      float f0 = 0.f, f1 = 0.f, f2 = 0.f;
      if ((unsigned)E < LIN) f0 = xc[E];
      if ((unsigned)(E + 1) < LIN) f1 = xc[E + 1];
      if ((unsigned)(E + 2) < LIN) f2 = xc[E + 2];
      h2v A; A.x = (_Float16)f0; A.y = (_Float16)f1;
      h2v Bv; Bv.x = (_Float16)f1; Bv.y = (_Float16)f2;
      As[c * DW + d] = __builtin_bit_cast(float, A);
      Bs[c * DW + d] = __builtin_bit_cast(float, Bv);
    }
    __syncthreads();

    if (tid < TP1) {                       // conv1 + pool: one pooled t per thread
      float s[O1] = {0.f, 0.f, 0.f, 0.f, 0.f, 0.f};
#pragma unroll
      for (int c = 0; c < C1; ++c) {
        const float* Ac = As + c * DW + tid;
        const float* Bc = Bs + c * DW + tid;
        h2v aA[O1], aB[O1];
#pragma unroll
        for (int o = 0; o < O1; ++o) {
          aA[o].x = BIGH; aA[o].y = BIGH;
          aB[o].x = BIGH; aB[o].y = BIGH;
        }
#pragma unroll 2
        for (int mc = 0; mc < 10; ++mc) {
          const int m4 = 4 * mc;
          // stride-1 lane access -> conflict-free LDS
          float a0 = Ac[m4], a1 = Ac[m4 + 1], a2 = Ac[m4 + 2], a3 = Ac[m4 + 3];
          float b0 = Bc[m4], b1 = Bc[m4 + 1], b2 = Bc[m4 + 2], b3 = Bc[m4 + 3];
          h2v A0 = bch2(a0), A1 = bch2(a1), A2 = bch2(a2), A3 = bch2(a3);
          h2v B0 = bch2(b0), B1 = bch2(b1), B2 = bch2(b2), B3 = bch2(b3);
#pragma unroll
          for (int o = 0; o < O1; ++o) {
            float4 wq = *(const float4*)&whb[(o * C1 + c) * 40 + m4];  // uniform -> s_load
            h2v w0 = bch2(wq.x), w1v = bch2(wq.y), w2v = bch2(wq.z), w3v = bch2(wq.w);
            aA[o] = __builtin_elementwise_min(aA[o], A0 + w0);
            aB[o] = __builtin_elementwise_min(aB[o], B0 + w0);
            aA[o] = __builtin_elementwise_min(aA[o], A1 + w1v);
            aB[o] = __builtin_elementwise_min(aB[o], B1 + w1v);
            aA[o] = __builtin_elementwise_min(aA[o], A2 + w2v);
            aB[o] = __builtin_elementwise_min(aB[o], B2 + w2v);
            aA[o] = __builtin_elementwise_min(aA[o], A3 + w3v);
            aB[o] = __builtin_elementwise_min(aB[o], B3 + w3v);
          }
        }
#pragma unroll
        for (int o = 0; o < O1; ++o)
          s[o] += fminf((float)aA[o].x, (float)aA[o].y) +
                  fminf((float)aB[o].x, (float)aB[o].y);
      }
#pragma unroll
      for (int o = 0; o < O1; ++o) P1[o * TP1 + tid] = 0.5f * s[o];
    }
    __syncthreads();

    if (tid < QJ) {                        // conv2 + pool from LDS, write p2h (f16)
      const int j = qq * QJ + tid;
      float xv[O1][4];
#pragma unroll
      for (int c = 0; c < O1; ++c) {
        xv[c][0] = P1[c * TP1 + 2 * tid];     xv[c][1] = P1[c * TP1 + 2 * tid + 1];
        xv[c][2] = P1[c * TP1 + 2 * tid + 2]; xv[c][3] = P1[c * TP1 + 2 * tid + 3];
      }
#pragma unroll
      for (int o = 0; o < O2; ++o) {
        float s = 0.f;
#pragma unroll
        for (int c = 0; c < O1; ++c) {
          float w0  = W2[(o * O1 + c) * 3 + 0];
          float w1v = W2[(o * O1 + c) * 3 + 1];
          float w2v = W2[(o * O1 + c) * 3 + 2];
          float m0 = fmaxf(fmaxf(xv[c][0] + w0, xv[c][1] + w1v), xv[c][2] + w2v);
          float m1 = fmaxf(fmaxf(xv[c][1] + w0, xv[c][2] + w1v), xv[c][3] + w2v);
          s += m0 + m1;
        }
        p2h[(size_t)b * NFLAT + o * LP2 + j] = (_Float16)(0.5f * s);
      }
    }
  }

  gbar(bar, 0);

  // ================= S3: FC1 via MFMA f16, split-K, atomicAdd into h1 =================
  if (blk < 254) {
    const int k0 = blk * 128;
    _Float16* bs = (_Float16*)smem;        // [64][128] f16, 16 KB (reuses conv smem)
    {
      const int row = tid >> 4, c4 = tid & 15;
      const int k = k0 + c4 * 8;
      float4 v = make_float4(0.f, 0.f, 0.f, 0.f);
      if (k + 8 <= NFLAT) v = *(const float4*)&p2h[(size_t)row * NFLAT + k];
      *(float4*)&bs[row * 128 + c4 * 8] = v;
    }
    __syncthreads();

    const int lane = tid & 63;
    const int wv   = tid >> 6;             // 0..15
    const int m_l  = lane & 15;
    const int q    = lane >> 4;
    const int mt   = wv >> 1;              // 0..7 -> M rows [mt*16, mt*16+16)
    const int np   = wv & 1;               // 0..1 -> N cols [np*32, np*32+32)
    const int m0   = mt * 16;

    int rowA = m0 + m_l;
    if (rowA >= H1) rowA = H1 - 1;         // pad rows: computed but not stored
    const float* wp = fc1w + (size_t)rowA * NFLAT;

    f32x4 acc0 = (f32x4){0.f, 0.f, 0.f, 0.f};
    f32x4 acc1 = (f32x4){0.f, 0.f, 0.f, 0.f};
#pragma unroll
    for (int ks = 0; ks < 4; ++ks) {
      int kk = k0 + ks * 32 + q * 8;
      if (kk + 8 > NFLAT) kk = NFLAT - 8;  // tail: B is zero there
      float4 al = *(const float4*)(wp + kk);
      float4 ah = *(const float4*)(wp + kk + 4);
      f16x8 A;
      A[0] = (_Float16)al.x; A[1] = (_Float16)al.y;
      A[2] = (_Float16)al.z; A[3] = (_Float16)al.w;
      A[4] = (_Float16)ah.x; A[5] = (_Float16)ah.y;
      A[6] = (_Float16)ah.z; A[7] = (_Float16)ah.w;
      f16x8 B0 = *(const f16x8*)&bs[(np * 32 + m_l) * 128 + ks * 32 + q * 8];
      f16x8 B1 = *(const f16x8*)&bs[(np * 32 + 16 + m_l) * 128 + ks * 32 + q * 8];
      acc0 = __builtin_amdgcn_mfma_f32_16x16x32_f16(A, B0, acc0, 0, 0, 0);
      acc1 = __builtin_amdgcn_mfma_f32_16x16x32_f16(A, B1, acc1, 0, 0, 0);
    }
    // D: row(m)=q*4+r, col(n)=m_l
#pragma unroll
    for (int r = 0; r < 4; ++r) {
      const int i = m0 + q * 4 + r;
      if (i < H1) {
        atomicAdd(&h1[i * 64 + np * 32 + m_l], acc0[r]);
        atomicAdd(&h1[i * 64 + np * 32 + 16 + m_l], acc1[r]);
      }
    }
  }

  gbar(bar, 1);

  // ================= S4: bias+ReLU, FC2+ReLU, FC3 =================
  if (blk < BB) {
    float* h1s = smem;            // 120
    float* h2s = smem + 128;      // 84
    const int b = blk;
    if (tid < H1) h1s[tid] = fmaxf(h1[tid * 64 + b] + fc1b[tid], 0.f);
    __syncthreads();
    if (tid < H2) {
      float s = fc2b[tid];
#pragma unroll 4
      for (int n = 0; n < H1; ++n) s += h1s[n] * fc2w[tid * H1 + n];
      h2s[tid] = fmaxf(s, 0.f);
    }
    __syncthreads();
    if (tid < NOUT) {
      float s = fc3b[tid];
#pragma unroll 4
      for (int n = 0; n < H2; ++n) s += h2s[n] * fc3w[tid * H2 + n];
      out[b * NOUT + tid] = s;
    }
  }
}

extern "C" void kernel_launch(void* const* d_in, const int* in_sizes, int n_in,
                              void* d_out, int out_size, void* d_ws, size_t ws_size,
                              hipStream_t stream) {
  const float* x     = (const float*)d_in[0];
  const float* w1    = (const float*)d_in[1];
  const float* w2    = (const float*)d_in[2];
  const float* fc1_w = (const float*)d_in[3];
  const float* fc1_b = (const float*)d_in[4];
  const float* fc2_w = (const float*)d_in[5];
  const float* fc2_b = (const float*)d_in[6];
  const float* fc3_w = (const float*)d_in[7];
  const float* fc3_b = (const float*)d_in[8];

  float* ws = (float*)d_ws;
  _Float16* p2h = (_Float16*)ws;                       // 64*32448 halves
  float*    h1  = ws + (size_t)BB * NFLAT / 2;         // 120*64 f32
  int*      bar = (int*)(h1 + (size_t)H1 * BB);        // 16 ints
  float*    whb = (float*)(bar + 16);                  // 720 f32
  float*    out = (float*)d_out;

  hipLaunchKernelGGL(k_prep, dim3(8), dim3(1024), 0, stream, w1, whb, h1, bar);
  hipLaunchKernelGGL(k_mega, dim3(NBLK), dim3(THR), 0, stream,
                     x, whb, w2, fc1_w, fc1_b, fc2_w, fc2_b, fc3_w, fc3_b,
                     p2h, h1, bar, out);
}

// Round 8
// 148.925 us; speedup vs baseline: 2.8617x; 2.8617x over previous
//
#include <hip/hip_runtime.h>

#define BB 64
#define C1 3
#define LIN 8192
#define PAD1 2
#define O1 6
#define KK1 80
#define LP1 4058       // pooled length after conv1(pad=2,K=80) + avgpool2

#define O2 16
#define KK2 3
#define LP2 2028

#define NFLAT 32448    // 16*2028 = 507*64
#define H1 120
#define H2 84
#define NOUT 10

typedef _Float16 h2 __attribute__((ext_vector_type(2)));
typedef _Float16 f16x8 __attribute__((ext_vector_type(8)));
typedef float f32x4 __attribute__((ext_vector_type(4)));
#define BIGH ((_Float16)30000.0f)

__device__ __forceinline__ h2 bch2(float f) { return __builtin_bit_cast(h2, f); }

// ---------------- Kernel 0: pack w1 into half2 pairs (w[2m], w[2m+1]) ----------------
__global__ __launch_bounds__(256) void k_prep(const float* __restrict__ w1,
                                              float* __restrict__ whb) {
  const int idx = threadIdx.x + blockIdx.x * 256;
  if (idx >= (O1 * C1) * (KK1 / 2)) return;
  const int oc = idx / (KK1 / 2);
  const int m  = idx - oc * (KK1 / 2);
  h2 v;
  v.x = (_Float16)w1[oc * KK1 + 2 * m];
  v.y = (_Float16)w1[oc * KK1 + 2 * m + 1];
  whb[idx] = __builtin_bit_cast(float, v);
}

// ---------------- Kernel 1: tropical min-plus conv1 + avgpool2, packed fp16 ----------------
// v3: x hoisted to VGPRs per (c, half) BEFORE the weight loop, so the inner
// loop is SMEM(s_load)+VALU only. Rationale: SMEM completes out-of-order ->
// any ds_read interleaved with s_load forces lgkmcnt(0) full drains (R6 was
// ~40us, ~4x the VALU floor). Separating the pipes removes the serialization.
#define TJ1 256
#define NT1 16
#define DW1 298

__global__ __launch_bounds__(256) void k_conv1(const float* __restrict__ x,
                                               const float* __restrict__ whb,
                                               float* __restrict__ p1) {
  __shared__ float AB[C1][2 * DW1 + 2];
  const int b    = blockIdx.x >> 4;
  const int tile = blockIdx.x & 15;
  const int j0   = tile * TJ1;
  const int T0   = 2 * j0;
  const int tid  = threadIdx.x;

  for (int q = tid; q < C1 * DW1; q += 256) {
    const int c = q / DW1;
    const int d = q - c * DW1;
    const int E = T0 + 2 * d - PAD1;
    const float* xc = x + ((size_t)b * C1 + c) * LIN;
    float f0 = 0.f, f1 = 0.f, f2 = 0.f;
    if ((unsigned)E < LIN) f0 = xc[E];
    if ((unsigned)(E + 1) < LIN) f1 = xc[E + 1];
    if ((unsigned)(E + 2) < LIN) f2 = xc[E + 2];
    h2 A; A.x = (_Float16)f0; A.y = (_Float16)f1;
    h2 Bv; Bv.x = (_Float16)f1; Bv.y = (_Float16)f2;
    AB[c][2 * d]     = __builtin_bit_cast(float, A);
    AB[c][2 * d + 1] = __builtin_bit_cast(float, Bv);
  }
  __syncthreads();

  const int jj = tid;
  const int j  = j0 + jj;

  float s0 = 0.f, s1 = 0.f, s2 = 0.f, s3 = 0.f, s4 = 0.f, s5 = 0.f;

#pragma unroll
  for (int c = 0; c < C1; ++c) {
    h2 aA[O1], aB[O1];
#pragma unroll
    for (int o = 0; o < O1; ++o) {
      aA[o].x = BIGH; aA[o].y = BIGH;
      aB[o].x = BIGH; aB[o].y = BIGH;
    }
#pragma unroll
    for (int hh = 0; hh < 2; ++hh) {
      // hoist 20 (A_m, B_m) float2s into VGPRs — one LDS burst, drained once
      float2 xv[20];
#pragma unroll
      for (int m = 0; m < 20; ++m)
        xv[m] = *(const float2*)&AB[c][2 * (jj + hh * 20 + m)];
#pragma unroll
      for (int o = 0; o < O1; ++o) {
        const float4* wp = (const float4*)&whb[(o * C1 + c) * 40 + hh * 20];
#pragma unroll
        for (int mq = 0; mq < 5; ++mq) {
          float4 wq = wp[mq];                 // uniform -> s_load_dwordx4
          h2 w0 = bch2(wq.x), w1v = bch2(wq.y), w2v = bch2(wq.z), w3v = bch2(wq.w);
          h2 A0 = bch2(xv[mq * 4 + 0].x), B0 = bch2(xv[mq * 4 + 0].y);
          h2 A1 = bch2(xv[mq * 4 + 1].x), B1 = bch2(xv[mq * 4 + 1].y);
          h2 A2 = bch2(xv[mq * 4 + 2].x), B2 = bch2(xv[mq * 4 + 2].y);
          h2 A3 = bch2(xv[mq * 4 + 3].x), B3 = bch2(xv[mq * 4 + 3].y);
          aA[o] = __builtin_elementwise_min(aA[o], A0 + w0);
          aB[o] = __builtin_elementwise_min(aB[o], B0 + w0);
          aA[o] = __builtin_elementwise_min(aA[o], A1 + w1v);
          aB[o] = __builtin_elementwise_min(aB[o], B1 + w1v);
          aA[o] = __builtin_elementwise_min(aA[o], A2 + w2v);
          aB[o] = __builtin_elementwise_min(aB[o], B2 + w2v);
          aA[o] = __builtin_elementwise_min(aA[o], A3 + w3v);
          aB[o] = __builtin_elementwise_min(aB[o], B3 + w3v);
        }
      }
    }
    float r[O1];
#pragma unroll
    for (int o = 0; o < O1; ++o)
      r[o] = fminf((float)aA[o].x, (float)aA[o].y) + fminf((float)aB[o].x, (float)aB[o].y);
    s0 += r[0]; s1 += r[1]; s2 += r[2]; s3 += r[3]; s4 += r[4]; s5 += r[5];
  }
  if (j < LP1) {
    float* pb = p1 + (size_t)b * O1 * LP1 + j;
    pb[0 * LP1] = 0.5f * s0;
    pb[1 * LP1] = 0.5f * s1;
    pb[2 * LP1] = 0.5f * s2;
    pb[3 * LP1] = 0.5f * s3;
    pb[4 * LP1] = 0.5f * s4;
    pb[5 * LP1] = 0.5f * s5;
  }
}

// ---------------- Kernel 2: tropical max-plus conv2 (K=3) + avgpool2 -> f16 ----------------
#define T2 256
#define XT2 516

__global__ __launch_bounds__(256) void k_conv2(const float* __restrict__ p1,
                                               const float* __restrict__ w2,
                                               _Float16* __restrict__ p2h) {
  __shared__ float ps[O1][XT2];
  __shared__ float w2s[O2 * O1 * KK2];   // 288 floats
  const int b    = blockIdx.x >> 3;
  const int tile = blockIdx.x & 7;
  const int j0   = tile * T2;
  const int tid  = threadIdx.x;

  for (int idx = tid; idx < O2 * O1 * KK2; idx += 256) w2s[idx] = w2[idx];
  for (int idx = tid; idx < O1 * XT2; idx += 256) {
    int c = idx / XT2;
    int p = idx - c * XT2;
    int t = 2 * j0 + p;
    ps[c][p] = (t < LP1) ? p1[((size_t)b * O1 + c) * LP1 + t] : 0.f;
  }
  __syncthreads();

  const int j = j0 + tid;
  if (j >= LP2) return;
  const int lb = 2 * tid;
  float xv[O1][4];
#pragma unroll
  for (int c = 0; c < O1; ++c) {
    xv[c][0] = ps[c][lb];     xv[c][1] = ps[c][lb + 1];
    xv[c][2] = ps[c][lb + 2]; xv[c][3] = ps[c][lb + 3];
  }
#pragma unroll
  for (int o = 0; o < O2; ++o) {
    float s = 0.f;
#pragma unroll
    for (int c = 0; c < O1; ++c) {
      float w0  = w2s[(o * O1 + c) * KK2 + 0];
      float w1v = w2s[(o * O1 + c) * KK2 + 1];
      float w2v = w2s[(o * O1 + c) * KK2 + 2];
      float m0 = fmaxf(fmaxf(xv[c][0] + w0, xv[c][1] + w1v), xv[c][2] + w2v);
      float m1 = fmaxf(fmaxf(xv[c][1] + w0, xv[c][2] + w1v), xv[c][3] + w2v);
      s += m0 + m1;
    }
    p2h[(size_t)b * NFLAT + o * LP2 + j] = (_Float16)(0.5f * s);
  }
}

// ---------------- Kernel 3: FC1 split-K via MFMA f16 ----------------
#define KC2 64
#define NKC2 507

__global__ __launch_bounds__(256) void k_fc1(const _Float16* __restrict__ p2h,
                                             const float* __restrict__ w,
                                             _Float16* __restrict__ part) {
  __shared__ _Float16 bs[64][KC2];    // [b][k], 8 KB
  const int kc  = blockIdx.x;
  const int k0  = kc * KC2;
  const int tid = threadIdx.x;

#pragma unroll
  for (int r = 0; r < 2; ++r) {
    const int task = tid + 256 * r;        // 0..511
    const int row  = task >> 3;
    const int c4   = task & 7;
    float4 v = *(const float4*)&p2h[(size_t)row * NFLAT + k0 + c4 * 8];
    *(float4*)&bs[row][c4 * 8] = v;
  }
  __syncthreads();

  const int lane = tid & 63;
  const int wid  = tid >> 6;             // 0..3
  const int m_l  = lane & 15;
  const int q    = lane >> 4;            // 0..3
  const int m0   = wid * 32;

  const int rowA0 = m0 + m_l;            // <= 111, always valid
  int rowA1 = m0 + 16 + m_l;             // <= 127; clamp pad rows
  if (rowA1 > H1 - 1) rowA1 = H1 - 1;
  const float* wp0 = w + (size_t)rowA0 * NFLAT + k0 + q * 8;
  const float* wp1 = w + (size_t)rowA1 * NFLAT + k0 + q * 8;

  f32x4 acc[2][4];
#pragma unroll
  for (int t = 0; t < 2; ++t)
#pragma unroll
    for (int nt = 0; nt < 4; ++nt) acc[t][nt] = (f32x4){0.f, 0.f, 0.f, 0.f};

#pragma unroll
  for (int ks = 0; ks < 2; ++ks) {
    float4 a0l = *(const float4*)(wp0 + ks * 32);
    float4 a0h = *(const float4*)(wp0 + ks * 32 + 4);
    float4 a1l = *(const float4*)(wp1 + ks * 32);
    float4 a1h = *(const float4*)(wp1 + ks * 32 + 4);
    f16x8 A0, A1;
    A0[0] = (_Float16)a0l.x; A0[1] = (_Float16)a0l.y;
    A0[2] = (_Float16)a0l.z; A0[3] = (_Float16)a0l.w;
    A0[4] = (_Float16)a0h.x; A0[5] = (_Float16)a0h.y;
    A0[6] = (_Float16)a0h.z; A0[7] = (_Float16)a0h.w;
    A1[0] = (_Float16)a1l.x; A1[1] = (_Float16)a1l.y;
    A1[2] = (_Float16)a1l.z; A1[3] = (_Float16)a1l.w;
    A1[4] = (_Float16)a1h.x; A1[5] = (_Float16)a1h.y;
    A1[6] = (_Float16)a1h.z; A1[7] = (_Float16)a1h.w;
#pragma unroll
    for (int nt = 0; nt < 4; ++nt) {
      f16x8 Bf = *(const f16x8*)&bs[nt * 16 + m_l][ks * 32 + q * 8];
      acc[0][nt] = __builtin_amdgcn_mfma_f32_16x16x32_f16(A0, Bf, acc[0][nt], 0, 0, 0);
      acc[1][nt] = __builtin_amdgcn_mfma_f32_16x16x32_f16(A1, Bf, acc[1][nt], 0, 0, 0);
    }
  }

#pragma unroll
  for (int t = 0; t < 2; ++t)
#pragma unroll
    for (int nt = 0; nt < 4; ++nt)
#pragma unroll
      for (int r = 0; r < 4; ++r) {
        const int i = m0 + t * 16 + q * 4 + r;
        if (i < H1)
          part[((size_t)kc * H1 + i) * 64 + nt * 16 + m_l] = (_Float16)acc[t][nt][r];
      }
}

// ---------------- Kernel 3b: reduce partials -> part2[4][120][64] f32 ----------------
__global__ __launch_bounds__(512) void k_fc1red(const _Float16* __restrict__ part,
                                                float* __restrict__ part2) {
  __shared__ float red[512];
  const int bx  = blockIdx.x;            // 0..479
  const int s   = bx / H1;               // 0..3
  const int i   = bx - s * H1;           // 0..119
  const int tid = threadIdx.x;
  const int b   = tid & 63;
  const int sub = tid >> 6;              // 0..7
  const int kc0 = s * 127;
  const int kc1 = (kc0 + 127 < NKC2) ? kc0 + 127 : NKC2;
  float acc = 0.f;
  for (int kc = kc0 + sub; kc < kc1; kc += 8)
    acc += (float)part[((size_t)kc * H1 + i) * 64 + b];
  red[tid] = acc;
  __syncthreads();
  if (tid < 64) {
    float t = 0.f;
#pragma unroll
    for (int s2 = 0; s2 < 8; ++s2) t += red[b + 64 * s2];
    part2[((size_t)s * H1 + i) * 64 + b] = t;
  }
}

// ---------------- Kernel 4: bias+ReLU, FC2+ReLU, FC3 ----------------
__global__ __launch_bounds__(128) void k_head(const float* __restrict__ part2,
                                              const float* __restrict__ fc1_b,
                                              const float* __restrict__ fc2_w,
                                              const float* __restrict__ fc2_b,
                                              const float* __restrict__ fc3_w,
                                              const float* __restrict__ fc3_b,
                                              float* __restrict__ out) {
  __shared__ float h1s[H1];
  __shared__ float h2s[H2];
  const int b = blockIdx.x;
  const int tid = threadIdx.x;
  if (tid < H1) {
    float v = part2[((size_t)0 * H1 + tid) * 64 + b]
            + part2[((size_t)1 * H1 + tid) * 64 + b]
            + part2[((size_t)2 * H1 + tid) * 64 + b]
            + part2[((size_t)3 * H1 + tid) * 64 + b];
    h1s[tid] = fmaxf(v + fc1_b[tid], 0.f);
  }
  __syncthreads();
  if (tid < H2) {
    float s = fc2_b[tid];
#pragma unroll 4
    for (int n = 0; n < H1; ++n) s += h1s[n] * fc2_w[tid * H1 + n];
    h2s[tid] = fmaxf(s, 0.f);
  }
  __syncthreads();
  if (tid < NOUT) {
    float s = fc3_b[tid];
#pragma unroll 4
    for (int n = 0; n < H2; ++n) s += h2s[n] * fc3_w[tid * H2 + n];
    out[b * NOUT + tid] = s;
  }
}

extern "C" void kernel_launch(void* const* d_in, const int* in_sizes, int n_in,
                              void* d_out, int out_size, void* d_ws, size_t ws_size,
                              hipStream_t stream) {
  const float* x     = (const float*)d_in[0];
  const float* w1    = (const float*)d_in[1];
  const float* w2    = (const float*)d_in[2];
  const float* fc1_w = (const float*)d_in[3];
  const float* fc1_b = (const float*)d_in[4];
  const float* fc2_w = (const float*)d_in[5];
  const float* fc2_b = (const float*)d_in[6];
  const float* fc3_w = (const float*)d_in[7];
  const float* fc3_b = (const float*)d_in[8];

  float* ws = (float*)d_ws;
  float*     p1    = ws;                                        // 1,558,272 f
  _Float16*  p2h   = (_Float16*)(p1 + (size_t)BB * O1 * LP1);   // 2,076,672 h
  _Float16*  part  = p2h + (size_t)BB * NFLAT;                  // 507*120*64 h
  float*     part2 = (float*)(part + (size_t)NKC2 * H1 * 64);   // 4*120*64 f
  float*     whb   = part2 + (size_t)4 * H1 * 64;               // 720 f
  float*     out   = (float*)d_out;

  hipLaunchKernelGGL(k_prep, dim3(3), dim3(256), 0, stream, w1, whb);
  hipLaunchKernelGGL(k_conv1, dim3(BB * NT1), dim3(256), 0, stream, x, whb, p1);
  hipLaunchKernelGGL(k_conv2, dim3(BB * 8), dim3(256), 0, stream, p1, w2, p2h);
  hipLaunchKernelGGL(k_fc1, dim3(NKC2), dim3(256), 0, stream, p2h, fc1_w, part);
  hipLaunchKernelGGL(k_fc1red, dim3(4 * H1), dim3(512), 0, stream, part, part2);
  hipLaunchKernelGGL(k_head, dim3(BB), dim3(128), 0, stream, part2, fc1_b, fc2_w, fc2_b,
                     fc3_w, fc3_b, out);
}

// Round 9
// 148.685 us; speedup vs baseline: 2.8663x; 1.0016x over previous
//
#include <hip/hip_runtime.h>

#define BB 64
#define C1 3
#define LIN 8192
#define PAD1 2
#define O1 6
#define KK1 80
#define LP1 4058       // pooled length after conv1(pad=2,K=80) + avgpool2

#define O2 16
#define KK2 3
#define LP2 2028

#define NFLAT 32448    // 16*2028 = 507*64
#define H1 120
#define H2 84
#define NOUT 10

typedef _Float16 h2 __attribute__((ext_vector_type(2)));
typedef _Float16 f16x8 __attribute__((ext_vector_type(8)));
typedef float f32x4 __attribute__((ext_vector_type(4)));
#define BIGH ((_Float16)30000.0f)

__device__ __forceinline__ h2 bch2(float f) { return __builtin_bit_cast(h2, f); }

// ---------------- Kernel 0: pack w1 into half2 pairs (w[2m], w[2m+1]) ----------------
__global__ __launch_bounds__(256) void k_prep(const float* __restrict__ w1,
                                              float* __restrict__ whb) {
  const int idx = threadIdx.x + blockIdx.x * 256;
  if (idx >= (O1 * C1) * (KK1 / 2)) return;
  const int oc = idx / (KK1 / 2);
  const int m  = idx - oc * (KK1 / 2);
  h2 v;
  v.x = (_Float16)w1[oc * KK1 + 2 * m];
  v.y = (_Float16)w1[oc * KK1 + 2 * m + 1];
  whb[idx] = __builtin_bit_cast(float, v);
}

// ---------------- Kernel 1: tropical min-plus conv1 + avgpool2, packed fp16 ----------------
// v4: (1) weights staged to LDS, read as uniform-address ds_read_b128
// broadcasts — no SMEM in the hot loop (in-order lgkmcnt, pipelinable);
// (2) 2 pooled j per thread — weight reads amortized 2x;
// (3) loops kept ROLLED (body ~3KB << 32KB I$) — R8's fully-unrolled body
// was ~23KB+ and a suspected i-fetch staller.
#define TJ1 512
#define NT1 8          // 8 tiles x 512 = 4096 >= LP1
#define DWIN 552
#define DPAD 556

__global__ __launch_bounds__(256) void k_conv1(const float* __restrict__ x,
                                               const float* __restrict__ whb,
                                               float* __restrict__ p1) {
  __shared__ float As[C1][DPAD];
  __shared__ float Bs[C1][DPAD];
  __shared__ float ws[O1 * C1 * 40];     // 720 dwords (h2-pair packed)
  const int b    = blockIdx.x >> 3;
  const int tile = blockIdx.x & 7;
  const int j0   = tile * TJ1;
  const int tid  = threadIdx.x;

  for (int idx = tid; idx < O1 * C1 * 40; idx += 256) ws[idx] = whb[idx];
  for (int q = tid; q < C1 * DWIN; q += 256) {
    const int c = q / DWIN;
    const int d = q - c * DWIN;
    const int E = 2 * (j0 + d) - PAD1;   // even
    const float* xc = x + ((size_t)b * C1 + c) * LIN;
    float f0 = 0.f, f1 = 0.f, f2 = 0.f;
    if ((unsigned)E < LIN) f0 = xc[E];
    if ((unsigned)(E + 1) < LIN) f1 = xc[E + 1];
    if ((unsigned)(E + 2) < LIN) f2 = xc[E + 2];
    h2 A; A.x = (_Float16)f0; A.y = (_Float16)f1;
    h2 Bv; Bv.x = (_Float16)f1; Bv.y = (_Float16)f2;
    As[c][d] = __builtin_bit_cast(float, A);
    Bs[c][d] = __builtin_bit_cast(float, Bv);
  }
  __syncthreads();

  const int jj = tid;
  float r1[O1] = {0.f, 0.f, 0.f, 0.f, 0.f, 0.f};
  float r2[O1] = {0.f, 0.f, 0.f, 0.f, 0.f, 0.f};

  for (int c = 0; c < C1; ++c) {
    h2 a1A[O1], a1B[O1], a2A[O1], a2B[O1];
#pragma unroll
    for (int o = 0; o < O1; ++o) {
      a1A[o].x = BIGH; a1A[o].y = BIGH;  a1B[o].x = BIGH; a1B[o].y = BIGH;
      a2A[o].x = BIGH; a2A[o].y = BIGH;  a2B[o].x = BIGH; a2B[o].y = BIGH;
    }
#pragma unroll 2
    for (int mq = 0; mq < 10; ++mq) {
      float4 xa1 = *(const float4*)&As[c][jj + 4 * mq];
      float4 xb1 = *(const float4*)&Bs[c][jj + 4 * mq];
      float4 xa2 = *(const float4*)&As[c][jj + 256 + 4 * mq];
      float4 xb2 = *(const float4*)&Bs[c][jj + 256 + 4 * mq];
      h2 A10 = bch2(xa1.x), A11 = bch2(xa1.y), A12 = bch2(xa1.z), A13 = bch2(xa1.w);
      h2 B10 = bch2(xb1.x), B11 = bch2(xb1.y), B12 = bch2(xb1.z), B13 = bch2(xb1.w);
      h2 A20 = bch2(xa2.x), A21 = bch2(xa2.y), A22 = bch2(xa2.z), A23 = bch2(xa2.w);
      h2 B20 = bch2(xb2.x), B21 = bch2(xb2.y), B22 = bch2(xb2.z), B23 = bch2(xb2.w);
#pragma unroll
      for (int o = 0; o < O1; ++o) {
        float4 wq = *(const float4*)&ws[(o * C1 + c) * 40 + 4 * mq];  // uniform -> broadcast
        h2 w0 = bch2(wq.x), w1v = bch2(wq.y), w2v = bch2(wq.z), w3v = bch2(wq.w);
        a1A[o] = __builtin_elementwise_min(a1A[o], A10 + w0);
        a1B[o] = __builtin_elementwise_min(a1B[o], B10 + w0);
        a1A[o] = __builtin_elementwise_min(a1A[o], A11 + w1v);
        a1B[o] = __builtin_elementwise_min(a1B[o], B11 + w1v);
        a1A[o] = __builtin_elementwise_min(a1A[o], A12 + w2v);
        a1B[o] = __builtin_elementwise_min(a1B[o], B12 + w2v);
        a1A[o] = __builtin_elementwise_min(a1A[o], A13 + w3v);
        a1B[o] = __builtin_elementwise_min(a1B[o], B13 + w3v);
        a2A[o] = __builtin_elementwise_min(a2A[o], A20 + w0);
        a2B[o] = __builtin_elementwise_min(a2B[o], B20 + w0);
        a2A[o] = __builtin_elementwise_min(a2A[o], A21 + w1v);
        a2B[o] = __builtin_elementwise_min(a2B[o], B21 + w1v);
        a2A[o] = __builtin_elementwise_min(a2A[o], A22 + w2v);
        a2B[o] = __builtin_elementwise_min(a2B[o], B22 + w2v);
        a2A[o] = __builtin_elementwise_min(a2A[o], A23 + w3v);
        a2B[o] = __builtin_elementwise_min(a2B[o], B23 + w3v);
      }
    }
#pragma unroll
    for (int o = 0; o < O1; ++o) {
      r1[o] += fminf((float)a1A[o].x, (float)a1A[o].y) +
               fminf((float)a1B[o].x, (float)a1B[o].y);
      r2[o] += fminf((float)a2A[o].x, (float)a2A[o].y) +
               fminf((float)a2B[o].x, (float)a2B[o].y);
    }
  }

  const int j1 = j0 + jj;
  const int j2 = j0 + 256 + jj;
  if (j1 < LP1) {
    float* pb = p1 + (size_t)b * O1 * LP1 + j1;
#pragma unroll
    for (int o = 0; o < O1; ++o) pb[o * LP1] = 0.5f * r1[o];
  }
  if (j2 < LP1) {
    float* pb = p1 + (size_t)b * O1 * LP1 + j2;
#pragma unroll
    for (int o = 0; o < O1; ++o) pb[o * LP1] = 0.5f * r2[o];
  }
}

// ---------------- Kernel 2: tropical max-plus conv2 (K=3) + avgpool2 -> f16 ----------------
#define T2 256
#define XT2 516

__global__ __launch_bounds__(256) void k_conv2(const float* __restrict__ p1,
                                               const float* __restrict__ w2,
                                               _Float16* __restrict__ p2h) {
  __shared__ float ps[O1][XT2];
  __shared__ float w2s[O2 * O1 * KK2];   // 288 floats
  const int b    = blockIdx.x >> 3;
  const int tile = blockIdx.x & 7;
  const int j0   = tile * T2;
  const int tid  = threadIdx.x;

  for (int idx = tid; idx < O2 * O1 * KK2; idx += 256) w2s[idx] = w2[idx];
  for (int idx = tid; idx < O1 * XT2; idx += 256) {
    int c = idx / XT2;
    int p = idx - c * XT2;
    int t = 2 * j0 + p;
    ps[c][p] = (t < LP1) ? p1[((size_t)b * O1 + c) * LP1 + t] : 0.f;
  }
  __syncthreads();

  const int j = j0 + tid;
  if (j >= LP2) return;
  const int lb = 2 * tid;
  float xv[O1][4];
#pragma unroll
  for (int c = 0; c < O1; ++c) {
    xv[c][0] = ps[c][lb];     xv[c][1] = ps[c][lb + 1];
    xv[c][2] = ps[c][lb + 2]; xv[c][3] = ps[c][lb + 3];
  }
#pragma unroll
  for (int o = 0; o < O2; ++o) {
    float s = 0.f;
#pragma unroll
    for (int c = 0; c < O1; ++c) {
      float w0  = w2s[(o * O1 + c) * KK2 + 0];
      float w1v = w2s[(o * O1 + c) * KK2 + 1];
      float w2v = w2s[(o * O1 + c) * KK2 + 2];
      float m0 = fmaxf(fmaxf(xv[c][0] + w0, xv[c][1] + w1v), xv[c][2] + w2v);
      float m1 = fmaxf(fmaxf(xv[c][1] + w0, xv[c][2] + w1v), xv[c][3] + w2v);
      s += m0 + m1;
    }
    p2h[(size_t)b * NFLAT + o * LP2 + j] = (_Float16)(0.5f * s);
  }
}

// ---------------- Kernel 3: FC1 split-K via MFMA f16 ----------------
#define KC2 64
#define NKC2 507

__global__ __launch_bounds__(256) void k_fc1(const _Float16* __restrict__ p2h,
                                             const float* __restrict__ w,
                                             _Float16* __restrict__ part) {
  __shared__ _Float16 bs[64][KC2];    // [b][k], 8 KB
  const int kc  = blockIdx.x;
  const int k0  = kc * KC2;
  const int tid = threadIdx.x;

#pragma unroll
  for (int r = 0; r < 2; ++r) {
    const int task = tid + 256 * r;        // 0..511
    const int row  = task >> 3;
    const int c4   = task & 7;
    float4 v = *(const float4*)&p2h[(size_t)row * NFLAT + k0 + c4 * 8];
    *(float4*)&bs[row][c4 * 8] = v;
  }
  __syncthreads();

  const int lane = tid & 63;
  const int wid  = tid >> 6;             // 0..3
  const int m_l  = lane & 15;
  const int q    = lane >> 4;            // 0..3
  const int m0   = wid * 32;

  const int rowA0 = m0 + m_l;            // <= 111, always valid
  int rowA1 = m0 + 16 + m_l;             // <= 127; clamp pad rows
  if (rowA1 > H1 - 1) rowA1 = H1 - 1;
  const float* wp0 = w + (size_t)rowA0 * NFLAT + k0 + q * 8;
  const float* wp1 = w + (size_t)rowA1 * NFLAT + k0 + q * 8;

  f32x4 acc[2][4];
#pragma unroll
  for (int t = 0; t < 2; ++t)
#pragma unroll
    for (int nt = 0; nt < 4; ++nt) acc[t][nt] = (f32x4){0.f, 0.f, 0.f, 0.f};

#pragma unroll
  for (int ks = 0; ks < 2; ++ks) {
    float4 a0l = *(const float4*)(wp0 + ks * 32);
    float4 a0h = *(const float4*)(wp0 + ks * 32 + 4);
    float4 a1l = *(const float4*)(wp1 + ks * 32);
    float4 a1h = *(const float4*)(wp1 + ks * 32 + 4);
    f16x8 A0, A1;
    A0[0] = (_Float16)a0l.x; A0[1] = (_Float16)a0l.y;
    A0[2] = (_Float16)a0l.z; A0[3] = (_Float16)a0l.w;
    A0[4] = (_Float16)a0h.x; A0[5] = (_Float16)a0h.y;
    A0[6] = (_Float16)a0h.z; A0[7] = (_Float16)a0h.w;
    A1[0] = (_Float16)a1l.x; A1[1] = (_Float16)a1l.y;
    A1[2] = (_Float16)a1l.z; A1[3] = (_Float16)a1l.w;
    A1[4] = (_Float16)a1h.x; A1[5] = (_Float16)a1h.y;
    A1[6] = (_Float16)a1h.z; A1[7] = (_Float16)a1h.w;
#pragma unroll
    for (int nt = 0; nt < 4; ++nt) {
      f16x8 Bf = *(const f16x8*)&bs[nt * 16 + m_l][ks * 32 + q * 8];
      acc[0][nt] = __builtin_amdgcn_mfma_f32_16x16x32_f16(A0, Bf, acc[0][nt], 0, 0, 0);
      acc[1][nt] = __builtin_amdgcn_mfma_f32_16x16x32_f16(A1, Bf, acc[1][nt], 0, 0, 0);
    }
  }

#pragma unroll
  for (int t = 0; t < 2; ++t)
#pragma unroll
    for (int nt = 0; nt < 4; ++nt)
#pragma unroll
      for (int r = 0; r < 4; ++r) {
        const int i = m0 + t * 16 + q * 4 + r;
        if (i < H1)
          part[((size_t)kc * H1 + i) * 64 + nt * 16 + m_l] = (_Float16)acc[t][nt][r];
      }
}

// ---------------- Kernel 3b: reduce partials -> part2[4][120][64] f32 ----------------
__global__ __launch_bounds__(512) void k_fc1red(const _Float16* __restrict__ part,
                                                float* __restrict__ part2) {
  __shared__ float red[512];
  const int bx  = blockIdx.x;            // 0..479
  const int s   = bx / H1;               // 0..3
  const int i   = bx - s * H1;           // 0..119
  const int tid = threadIdx.x;
  const int b   = tid & 63;
  const int sub = tid >> 6;              // 0..7
  const int kc0 = s * 127;
  const int kc1 = (kc0 + 127 < NKC2) ? kc0 + 127 : NKC2;
  float acc = 0.f;
  for (int kc = kc0 + sub; kc < kc1; kc += 8)
    acc += (float)part[((size_t)kc * H1 + i) * 64 + b];
  red[tid] = acc;
  __syncthreads();
  if (tid < 64) {
    float t = 0.f;
#pragma unroll
    for (int s2 = 0; s2 < 8; ++s2) t += red[b + 64 * s2];
    part2[((size_t)s * H1 + i) * 64 + b] = t;
  }
}

// ---------------- Kernel 4: bias+ReLU, FC2+ReLU, FC3 ----------------
__global__ __launch_bounds__(128) void k_head(const float* __restrict__ part2,
                                              const float* __restrict__ fc1_b,
                                              const float* __restrict__ fc2_w,
                                              const float* __restrict__ fc2_b,
                                              const float* __restrict__ fc3_w,
                                              const float* __restrict__ fc3_b,
                                              float* __restrict__ out) {
  __shared__ float h1s[H1];
  __shared__ float h2s[H2];
  const int b = blockIdx.x;
  const int tid = threadIdx.x;
  if (tid < H1) {
    float v = part2[((size_t)0 * H1 + tid) * 64 + b]
            + part2[((size_t)1 * H1 + tid) * 64 + b]
            + part2[((size_t)2 * H1 + tid) * 64 + b]
            + part2[((size_t)3 * H1 + tid) * 64 + b];
    h1s[tid] = fmaxf(v + fc1_b[tid], 0.f);
  }
  __syncthreads();
  if (tid < H2) {
    float s = fc2_b[tid];
#pragma unroll 4
    for (int n = 0; n < H1; ++n) s += h1s[n] * fc2_w[tid * H1 + n];
    h2s[tid] = fmaxf(s, 0.f);
  }
  __syncthreads();
  if (tid < NOUT) {
    float s = fc3_b[tid];
#pragma unroll 4
    for (int n = 0; n < H2; ++n) s += h2s[n] * fc3_w[tid * H2 + n];
    out[b * NOUT + tid] = s;
  }
}

extern "C" void kernel_launch(void* const* d_in, const int* in_sizes, int n_in,
                              void* d_out, int out_size, void* d_ws, size_t ws_size,
                              hipStream_t stream) {
  const float* x     = (const float*)d_in[0];
  const float* w1    = (const float*)d_in[1];
  const float* w2    = (const float*)d_in[2];
  const float* fc1_w = (const float*)d_in[3];
  const float* fc1_b = (const float*)d_in[4];
  const float* fc2_w = (const float*)d_in[5];
  const float* fc2_b = (const float*)d_in[6];
  const float* fc3_w = (const float*)d_in[7];
  const float* fc3_b = (const float*)d_in[8];

  float* ws = (float*)d_ws;
  float*     p1    = ws;                                        // 1,558,272 f
  _Float16*  p2h   = (_Float16*)(p1 + (size_t)BB * O1 * LP1);   // 2,076,672 h
  _Float16*  part  = p2h + (size_t)BB * NFLAT;                  // 507*120*64 h
  float*     part2 = (float*)(part + (size_t)NKC2 * H1 * 64);   // 4*120*64 f
  float*     whb   = part2 + (size_t)4 * H1 * 64;               // 720 f
  float*     out   = (float*)d_out;

  hipLaunchKernelGGL(k_prep, dim3(3), dim3(256), 0, stream, w1, whb);
  hipLaunchKernelGGL(k_conv1, dim3(BB * NT1), dim3(256), 0, stream, x, whb, p1);
  hipLaunchKernelGGL(k_conv2, dim3(BB * 8), dim3(256), 0, stream, p1, w2, p2h);
  hipLaunchKernelGGL(k_fc1, dim3(NKC2), dim3(256), 0, stream, p2h, fc1_w, part);
  hipLaunchKernelGGL(k_fc1red, dim3(4 * H1), dim3(512), 0, stream, part, part2);
  hipLaunchKernelGGL(k_head, dim3(BB), dim3(128), 0, stream, part2, fc1_b, fc2_w, fc2_b,
                     fc3_w, fc3_b, out);
}

// Round 10
// 146.515 us; speedup vs baseline: 2.9087x; 1.0148x over previous
//
#include <hip/hip_runtime.h>

#define BB 64
#define C1 3
#define LIN 8192
#define PAD1 2
#define O1 6
#define KK1 80
#define LP1 4058       // pooled length after conv1(pad=2,K=80) + avgpool2

#define O2 16
#define KK2 3
#define LP2 2028

#define NFLAT 32448    // 16*2028 = 507*64
#define H1 120
#define H2 84
#define NOUT 10

typedef _Float16 h2 __attribute__((ext_vector_type(2)));
typedef _Float16 f16x8 __attribute__((ext_vector_type(8)));
typedef float f32x4 __attribute__((ext_vector_type(4)));
#define BIGH ((_Float16)30000.0f)

__device__ __forceinline__ h2 bch2(float f) { return __builtin_bit_cast(h2, f); }
// B-pair from adjacent A-pairs: (A[d].hi, A[d+1].lo) via funnel shift -> v_alignbit
__device__ __forceinline__ h2 mkB(float nxt, float cur) {
  unsigned lo = __builtin_bit_cast(unsigned, cur);
  unsigned hi = __builtin_bit_cast(unsigned, nxt);
  return __builtin_bit_cast(h2, (lo >> 16) | (hi << 16));
}

// ---------------- Kernel 0: pack w1 into half2 pairs (w[2m], w[2m+1]) ----------------
__global__ __launch_bounds__(256) void k_prep(const float* __restrict__ w1,
                                              float* __restrict__ whb) {
  const int idx = threadIdx.x + blockIdx.x * 256;
  if (idx >= (O1 * C1) * (KK1 / 2)) return;
  const int oc = idx / (KK1 / 2);
  const int m  = idx - oc * (KK1 / 2);
  h2 v;
  v.x = (_Float16)w1[oc * KK1 + 2 * m];
  v.y = (_Float16)w1[oc * KK1 + 2 * m + 1];
  whb[idx] = __builtin_bit_cast(float, v);
}

// ---------------- Kernel 1: tropical min-plus conv1 + avgpool2, packed fp16 ----------------
// v5: FULL-OCCUPANCY build. 1024 blocks x 512 thr (__launch_bounds__(512,8)
// -> VGPR<=64) = 32 waves/CU. Per thread: 1 pooled j x 3 o (o-split by
// half-block). Single packed A array in LDS; odd-phase pairs derived in
// registers via v_alignbit (no B array, no B reads). Weights from LDS,
// uniform-address broadcast reads. Five prior conv1 variants all sat at
// ~43us with real-VALU ~25% => latency-bound at <=16 waves/CU; this attacks
// occupancy while keeping LDS-instr count ~120/thread and VALU near floor.
#define TJ1 256
#define NT1 16
#define DWIN 297
#define DPAD 304

__global__ __launch_bounds__(512, 8) void k_conv1(const float* __restrict__ x,
                                                  const float* __restrict__ whb,
                                                  float* __restrict__ p1) {
  __shared__ float As[C1][DPAD];
  __shared__ float ws[O1 * C1 * 40];     // 720 dwords (h2-pair packed)
  const int b    = blockIdx.x >> 4;
  const int tile = blockIdx.x & 15;
  const int j0   = tile * TJ1;
  const int tid  = threadIdx.x;          // 0..511

  for (int idx = tid; idx < O1 * C1 * 40; idx += 512) ws[idx] = whb[idx];
  for (int q = tid; q < C1 * DWIN; q += 512) {
    const int c = q / DWIN;
    const int d = q - c * DWIN;
    const int E = 2 * (j0 + d) - PAD1;
    const float* xc = x + ((size_t)b * C1 + c) * LIN;
    float f0 = 0.f, f1 = 0.f;
    if ((unsigned)E < LIN) f0 = xc[E];
    if ((unsigned)(E + 1) < LIN) f1 = xc[E + 1];
    h2 A; A.x = (_Float16)f0; A.y = (_Float16)f1;
    As[c][d] = __builtin_bit_cast(float, A);
  }
  __syncthreads();

  const int og = tid >> 8;               // 0/1 (wave-uniform)
  const int jj = tid & 255;
  const int ob = og * 3;                 // o in {ob, ob+1, ob+2}

  float r0 = 0.f, r1 = 0.f, r2 = 0.f;

  for (int c = 0; c < C1; ++c) {
    h2 aA[3], aB[3];
#pragma unroll
    for (int oo = 0; oo < 3; ++oo) {
      aA[oo].x = BIGH; aA[oo].y = BIGH;
      aB[oo].x = BIGH; aB[oo].y = BIGH;
    }
    float4 cur = *(const float4*)&As[c][jj];
#pragma unroll 2
    for (int mq = 0; mq < 10; ++mq) {
      float4 nxt = *(const float4*)&As[c][jj + 4 * mq + 4];
      h2 A0 = bch2(cur.x), A1 = bch2(cur.y), A2 = bch2(cur.z), A3 = bch2(cur.w);
      h2 B0 = mkB(cur.y, cur.x);
      h2 B1 = mkB(cur.z, cur.y);
      h2 B2 = mkB(cur.w, cur.z);
      h2 B3 = mkB(nxt.x, cur.w);
#pragma unroll
      for (int oo = 0; oo < 3; ++oo) {
        float4 wq = *(const float4*)&ws[((ob + oo) * C1 + c) * 40 + 4 * mq]; // uniform
        h2 w0 = bch2(wq.x), w1v = bch2(wq.y), w2v = bch2(wq.z), w3v = bch2(wq.w);
        aA[oo] = __builtin_elementwise_min(aA[oo], A0 + w0);
        aB[oo] = __builtin_elementwise_min(aB[oo], B0 + w0);
        aA[oo] = __builtin_elementwise_min(aA[oo], A1 + w1v);
        aB[oo] = __builtin_elementwise_min(aB[oo], B1 + w1v);
        aA[oo] = __builtin_elementwise_min(aA[oo], A2 + w2v);
        aB[oo] = __builtin_elementwise_min(aB[oo], B2 + w2v);
        aA[oo] = __builtin_elementwise_min(aA[oo], A3 + w3v);
        aB[oo] = __builtin_elementwise_min(aB[oo], B3 + w3v);
      }
      cur = nxt;
    }
    r0 += fminf((float)aA[0].x, (float)aA[0].y) + fminf((float)aB[0].x, (float)aB[0].y);
    r1 += fminf((float)aA[1].x, (float)aA[1].y) + fminf((float)aB[1].x, (float)aB[1].y);
    r2 += fminf((float)aA[2].x, (float)aA[2].y) + fminf((float)aB[2].x, (float)aB[2].y);
  }

  const int j = j0 + jj;
  if (j < LP1) {
    float* pb = p1 + (size_t)b * O1 * LP1 + j;
    pb[(ob + 0) * LP1] = 0.5f * r0;
    pb[(ob + 1) * LP1] = 0.5f * r1;
    pb[(ob + 2) * LP1] = 0.5f * r2;
  }
}

// ---------------- Kernel 2: tropical max-plus conv2 (K=3) + avgpool2 -> f16 ----------------
#define T2 256
#define XT2 516

__global__ __launch_bounds__(256) void k_conv2(const float* __restrict__ p1,
                                               const float* __restrict__ w2,
                                               _Float16* __restrict__ p2h) {
  __shared__ float ps[O1][XT2];
  __shared__ float w2s[O2 * O1 * KK2];   // 288 floats
  const int b    = blockIdx.x >> 3;
  const int tile = blockIdx.x & 7;
  const int j0   = tile * T2;
  const int tid  = threadIdx.x;

  for (int idx = tid; idx < O2 * O1 * KK2; idx += 256) w2s[idx] = w2[idx];
  for (int idx = tid; idx < O1 * XT2; idx += 256) {
    int c = idx / XT2;
    int p = idx - c * XT2;
    int t = 2 * j0 + p;
    ps[c][p] = (t < LP1) ? p1[((size_t)b * O1 + c) * LP1 + t] : 0.f;
  }
  __syncthreads();

  const int j = j0 + tid;
  if (j >= LP2) return;
  const int lb = 2 * tid;
  float xv[O1][4];
#pragma unroll
  for (int c = 0; c < O1; ++c) {
    xv[c][0] = ps[c][lb];     xv[c][1] = ps[c][lb + 1];
    xv[c][2] = ps[c][lb + 2]; xv[c][3] = ps[c][lb + 3];
  }
#pragma unroll
  for (int o = 0; o < O2; ++o) {
    float s = 0.f;
#pragma unroll
    for (int c = 0; c < O1; ++c) {
      float w0  = w2s[(o * O1 + c) * KK2 + 0];
      float w1v = w2s[(o * O1 + c) * KK2 + 1];
      float w2v = w2s[(o * O1 + c) * KK2 + 2];
      float m0 = fmaxf(fmaxf(xv[c][0] + w0, xv[c][1] + w1v), xv[c][2] + w2v);
      float m1 = fmaxf(fmaxf(xv[c][1] + w0, xv[c][2] + w1v), xv[c][3] + w2v);
      s += m0 + m1;
    }
    p2h[(size_t)b * NFLAT + o * LP2 + j] = (_Float16)(0.5f * s);
  }
}

// ---------------- Kernel 3: FC1 split-K via MFMA f16 ----------------
#define KC2 64
#define NKC2 507

__global__ __launch_bounds__(256) void k_fc1(const _Float16* __restrict__ p2h,
                                             const float* __restrict__ w,
                                             _Float16* __restrict__ part) {
  __shared__ _Float16 bs[64][KC2];    // [b][k], 8 KB
  const int kc  = blockIdx.x;
  const int k0  = kc * KC2;
  const int tid = threadIdx.x;

#pragma unroll
  for (int r = 0; r < 2; ++r) {
    const int task = tid + 256 * r;        // 0..511
    const int row  = task >> 3;
    const int c4   = task & 7;
    float4 v = *(const float4*)&p2h[(size_t)row * NFLAT + k0 + c4 * 8];
    *(float4*)&bs[row][c4 * 8] = v;
  }
  __syncthreads();

  const int lane = tid & 63;
  const int wid  = tid >> 6;             // 0..3
  const int m_l  = lane & 15;
  const int q    = lane >> 4;            // 0..3
  const int m0   = wid * 32;

  const int rowA0 = m0 + m_l;            // <= 111, always valid
  int rowA1 = m0 + 16 + m_l;             // <= 127; clamp pad rows
  if (rowA1 > H1 - 1) rowA1 = H1 - 1;
  const float* wp0 = w + (size_t)rowA0 * NFLAT + k0 + q * 8;
  const float* wp1 = w + (size_t)rowA1 * NFLAT + k0 + q * 8;

  f32x4 acc[2][4];
#pragma unroll
  for (int t = 0; t < 2; ++t)
#pragma unroll
    for (int nt = 0; nt < 4; ++nt) acc[t][nt] = (f32x4){0.f, 0.f, 0.f, 0.f};

#pragma unroll
  for (int ks = 0; ks < 2; ++ks) {
    float4 a0l = *(const float4*)(wp0 + ks * 32);
    float4 a0h = *(const float4*)(wp0 + ks * 32 + 4);
    float4 a1l = *(const float4*)(wp1 + ks * 32);
    float4 a1h = *(const float4*)(wp1 + ks * 32 + 4);
    f16x8 A0, A1;
    A0[0] = (_Float16)a0l.x; A0[1] = (_Float16)a0l.y;
    A0[2] = (_Float16)a0l.z; A0[3] = (_Float16)a0l.w;
    A0[4] = (_Float16)a0h.x; A0[5] = (_Float16)a0h.y;
    A0[6] = (_Float16)a0h.z; A0[7] = (_Float16)a0h.w;
    A1[0] = (_Float16)a1l.x; A1[1] = (_Float16)a1l.y;
    A1[2] = (_Float16)a1l.z; A1[3] = (_Float16)a1l.w;
    A1[4] = (_Float16)a1h.x; A1[5] = (_Float16)a1h.y;
    A1[6] = (_Float16)a1h.z; A1[7] = (_Float16)a1h.w;
#pragma unroll
    for (int nt = 0; nt < 4; ++nt) {
      f16x8 Bf = *(const f16x8*)&bs[nt * 16 + m_l][ks * 32 + q * 8];
      acc[0][nt] = __builtin_amdgcn_mfma_f32_16x16x32_f16(A0, Bf, acc[0][nt], 0, 0, 0);
      acc[1][nt] = __builtin_amdgcn_mfma_f32_16x16x32_f16(A1, Bf, acc[1][nt], 0, 0, 0);
    }
  }

#pragma unroll
  for (int t = 0; t < 2; ++t)
#pragma unroll
    for (int nt = 0; nt < 4; ++nt)
#pragma unroll
      for (int r = 0; r < 4; ++r) {
        const int i = m0 + t * 16 + q * 4 + r;
        if (i < H1)
          part[((size_t)kc * H1 + i) * 64 + nt * 16 + m_l] = (_Float16)acc[t][nt][r];
      }
}

// ---------------- Kernel 3b: reduce partials -> part2[4][120][64] f32 ----------------
__global__ __launch_bounds__(512) void k_fc1red(const _Float16* __restrict__ part,
                                                float* __restrict__ part2) {
  __shared__ float red[512];
  const int bx  = blockIdx.x;            // 0..479
  const int s   = bx / H1;               // 0..3
  const int i   = bx - s * H1;           // 0..119
  const int tid = threadIdx.x;
  const int b   = tid & 63;
  const int sub = tid >> 6;              // 0..7
  const int kc0 = s * 127;
  const int kc1 = (kc0 + 127 < NKC2) ? kc0 + 127 : NKC2;
  float acc = 0.f;
  for (int kc = kc0 + sub; kc < kc1; kc += 8)
    acc += (float)part[((size_t)kc * H1 + i) * 64 + b];
  red[tid] = acc;
  __syncthreads();
  if (tid < 64) {
    float t = 0.f;
#pragma unroll
    for (int s2 = 0; s2 < 8; ++s2) t += red[b + 64 * s2];
    part2[((size_t)s * H1 + i) * 64 + b] = t;
  }
}

// ---------------- Kernel 4: bias+ReLU, FC2+ReLU, FC3 ----------------
__global__ __launch_bounds__(128) void k_head(const float* __restrict__ part2,
                                              const float* __restrict__ fc1_b,
                                              const float* __restrict__ fc2_w,
                                              const float* __restrict__ fc2_b,
                                              const float* __restrict__ fc3_w,
                                              const float* __restrict__ fc3_b,
                                              float* __restrict__ out) {
  __shared__ float h1s[H1];
  __shared__ float h2s[H2];
  const int b = blockIdx.x;
  const int tid = threadIdx.x;
  if (tid < H1) {
    float v = part2[((size_t)0 * H1 + tid) * 64 + b]
            + part2[((size_t)1 * H1 + tid) * 64 + b]
            + part2[((size_t)2 * H1 + tid) * 64 + b]
            + part2[((size_t)3 * H1 + tid) * 64 + b];
    h1s[tid] = fmaxf(v + fc1_b[tid], 0.f);
  }
  __syncthreads();
  if (tid < H2) {
    float s = fc2_b[tid];
#pragma unroll 4
    for (int n = 0; n < H1; ++n) s += h1s[n] * fc2_w[tid * H1 + n];
    h2s[tid] = fmaxf(s, 0.f);
  }
  __syncthreads();
  if (tid < NOUT) {
    float s = fc3_b[tid];
#pragma unroll 4
    for (int n = 0; n < H2; ++n) s += h2s[n] * fc3_w[tid * H2 + n];
    out[b * NOUT + tid] = s;
  }
}

extern "C" void kernel_launch(void* const* d_in, const int* in_sizes, int n_in,
                              void* d_out, int out_size, void* d_ws, size_t ws_size,
                              hipStream_t stream) {
  const float* x     = (const float*)d_in[0];
  const float* w1    = (const float*)d_in[1];
  const float* w2    = (const float*)d_in[2];
  const float* fc1_w = (const float*)d_in[3];
  const float* fc1_b = (const float*)d_in[4];
  const float* fc2_w = (const float*)d_in[5];
  const float* fc2_b = (const float*)d_in[6];
  const float* fc3_w = (const float*)d_in[7];
  const float* fc3_b = (const float*)d_in[8];

  float* ws = (float*)d_ws;
  float*     p1    = ws;                                        // 1,558,272 f
  _Float16*  p2h   = (_Float16*)(p1 + (size_t)BB * O1 * LP1);   // 2,076,672 h
  _Float16*  part  = p2h + (size_t)BB * NFLAT;                  // 507*120*64 h
  float*     part2 = (float*)(part + (size_t)NKC2 * H1 * 64);   // 4*120*64 f
  float*     whb   = part2 + (size_t)4 * H1 * 64;               // 720 f
  float*     out   = (float*)d_out;

  hipLaunchKernelGGL(k_prep, dim3(3), dim3(256), 0, stream, w1, whb);
  hipLaunchKernelGGL(k_conv1, dim3(BB * NT1), dim3(512), 0, stream, x, whb, p1);
  hipLaunchKernelGGL(k_conv2, dim3(BB * 8), dim3(256), 0, stream, p1, w2, p2h);
  hipLaunchKernelGGL(k_fc1, dim3(NKC2), dim3(256), 0, stream, p2h, fc1_w, part);
  hipLaunchKernelGGL(k_fc1red, dim3(4 * H1), dim3(512), 0, stream, part, part2);
  hipLaunchKernelGGL(k_head, dim3(BB), dim3(128), 0, stream, part2, fc1_b, fc2_w, fc2_b,
                     fc3_w, fc3_b, out);
}